// Round 5
// baseline (245.089 us; speedup 1.0000x reference)
//
#include <hip/hip_runtime.h>

#define B_ 4
#define N_ 2048
#define D_ 512
#define H_ 8
#define DH_ 64
#define ROWS_ 8192

typedef float f32x4 __attribute__((ext_vector_type(4)));
typedef short short8v __attribute__((ext_vector_type(8)));
typedef short short4v __attribute__((ext_vector_type(4)));
typedef unsigned uint4v __attribute__((ext_vector_type(4)));

__device__ __forceinline__ short f2bf(float f) {
    unsigned u = __builtin_bit_cast(unsigned, f);
    u += 0x7FFFu + ((u >> 16) & 1u);   // round-to-nearest-even
    return (short)(u >> 16);
}

__device__ __forceinline__ unsigned cvtpk_bf16(float lo, float hi) {
    unsigned r;
    asm("v_cvt_pk_bf16_f32 %0, %1, %2" : "=v"(r) : "v"(lo), "v"(hi));
    return r;
}

// async global->LDS, 16B per lane; lds dest must be wave-uniform base.
__device__ __forceinline__ void gload16(const void* g, void* l) {
    __builtin_amdgcn_global_load_lds(
        (const __attribute__((address_space(1))) unsigned int*)g,
        (__attribute__((address_space(3))) unsigned int*)l, 16, 0, 0);
}

// ---------------------------------------------------------------------------
// LayerNorm fp32-in -> bf16-out. One wave per row of 512; 4 rows/block.
// ---------------------------------------------------------------------------
__global__ __launch_bounds__(256) void ln_bf16_kernel(const float* __restrict__ x,
                                                      const float* __restrict__ g,
                                                      const float* __restrict__ bb,
                                                      short* __restrict__ out) {
    int wave = threadIdx.x >> 6;
    int lane = threadIdx.x & 63;
    int row  = blockIdx.x * 4 + wave;
    const float* xr = x + (size_t)row * D_;

    float4 v0 = ((const float4*)xr)[lane * 2 + 0];
    float4 v1 = ((const float4*)xr)[lane * 2 + 1];

    float s = v0.x + v0.y + v0.z + v0.w + v1.x + v1.y + v1.z + v1.w;
    #pragma unroll
    for (int off = 32; off; off >>= 1) s += __shfl_xor(s, off, 64);
    float mu = s * (1.0f / D_);

    float d0 = v0.x - mu, d1 = v0.y - mu, d2 = v0.z - mu, d3 = v0.w - mu;
    float d4 = v1.x - mu, d5 = v1.y - mu, d6 = v1.z - mu, d7 = v1.w - mu;
    float vs = d0*d0 + d1*d1 + d2*d2 + d3*d3 + d4*d4 + d5*d5 + d6*d6 + d7*d7;
    #pragma unroll
    for (int off = 32; off; off >>= 1) vs += __shfl_xor(vs, off, 64);
    float rstd = rsqrtf(vs * (1.0f / D_) + 1e-5f);

    float4 g0 = ((const float4*)g)[lane * 2 + 0];
    float4 g1 = ((const float4*)g)[lane * 2 + 1];
    float4 b0 = ((const float4*)bb)[lane * 2 + 0];
    float4 b1 = ((const float4*)bb)[lane * 2 + 1];

    short8v ov;
    ov[0] = f2bf(d0 * rstd * g0.x + b0.x);
    ov[1] = f2bf(d1 * rstd * g0.y + b0.y);
    ov[2] = f2bf(d2 * rstd * g0.z + b0.z);
    ov[3] = f2bf(d3 * rstd * g0.w + b0.w);
    ov[4] = f2bf(d4 * rstd * g1.x + b1.x);
    ov[5] = f2bf(d5 * rstd * g1.y + b1.y);
    ov[6] = f2bf(d6 * rstd * g1.z + b1.z);
    ov[7] = f2bf(d7 * rstd * g1.w + b1.w);
    *(short8v*)&out[(size_t)row * D_ + lane * 8] = ov;
}

// ---------------------------------------------------------------------------
// Weight transpose + cvt: W[K][N] fp32 -> WT[N][K] bf16. 64x64 tile per block.
// ---------------------------------------------------------------------------
__global__ __launch_bounds__(256) void wt_kernel(const float* __restrict__ W,
                                                 short* __restrict__ WT,
                                                 int K, int N) {
    __shared__ short Ts[64][72];
    int tid = threadIdx.x;
    int n0 = blockIdx.x * 64, k0 = blockIdx.y * 64;

    #pragma unroll
    for (int i = 0; i < 4; ++i) {
        int idx = tid + i * 256;            // 1024 float4 chunks
        int k = idx >> 4, nq = (idx & 15) * 4;
        float4 wv = *(const float4*)&W[(size_t)(k0 + k) * N + n0 + nq];
        short4v t;
        t[0] = f2bf(wv.x); t[1] = f2bf(wv.y); t[2] = f2bf(wv.z); t[3] = f2bf(wv.w);
        *(short4v*)&Ts[k][nq] = t;
    }
    __syncthreads();

    int n = tid >> 2, kq = (tid & 3) * 16;
    short8v o0, o1;
    #pragma unroll
    for (int j = 0; j < 8; ++j) { o0[j] = Ts[kq + j][n]; o1[j] = Ts[kq + 8 + j][n]; }
    *(short8v*)&WT[(size_t)(n0 + n) * K + k0 + kq]     = o0;
    *(short8v*)&WT[(size_t)(n0 + n) * K + k0 + kq + 8] = o1;
}

// ---------------------------------------------------------------------------
// V transpose per head: qkv_bf[row][1536] (v at +1024) -> vtg[bh][64 d][2048 n]
// ---------------------------------------------------------------------------
__global__ __launch_bounds__(256) void vt_kernel(const short* __restrict__ qkvb,
                                                 short* __restrict__ vtg) {
    __shared__ short Ts[64][72];
    int tid = threadIdx.x;
    int n0 = blockIdx.x * 64;
    int bh = blockIdx.y;
    int b = bh >> 3, h = bh & 7;

    #pragma unroll
    for (int i = 0; i < 2; ++i) {
        int idx = tid + i * 256;            // 512 chunks of 8 bf16
        int n = idx >> 3, dq = (idx & 7) * 8;
        *(short8v*)&Ts[n][dq] =
            *(const short8v*)&qkvb[(size_t)(b * N_ + n0 + n) * 1536 + 1024 + h * 64 + dq];
    }
    __syncthreads();

    int d = tid >> 2, nq = (tid & 3) * 16;
    short8v o0, o1;
    #pragma unroll
    for (int j = 0; j < 8; ++j) { o0[j] = Ts[nq + j][d]; o1[j] = Ts[nq + 8 + j][d]; }
    size_t base = ((size_t)bh * 64 + d) * N_ + n0 + nq;
    *(short8v*)&vtg[base]     = o0;
    *(short8v*)&vtg[base + 8] = o1;
}

// ---------------------------------------------------------------------------
// bf16 MFMA GEMM, m97 structure: 128x128 tile, BK=64, global_load_lds width-16
// staging into LINEAR LDS [128][64], single-buffered, 2 barriers per K-step.
// C[M,N] = A[M,K] @ BT[N,K]^T + bias (+resid)(+gelu)
// ---------------------------------------------------------------------------
template<bool GELU, bool RESID, bool OUTBF>
__global__ __launch_bounds__(256) void gemm_bf16(const short* __restrict__ A,
                                                 const short* __restrict__ BT,
                                                 const float* __restrict__ bias,
                                                 const float* __restrict__ resid,
                                                 float* __restrict__ Cf,
                                                 short* __restrict__ Cb,
                                                 int M, int N, int K) {
    __shared__ short As[128 * 64];
    __shared__ short Bs[128 * 64];
    int tid = threadIdx.x;
    int l = tid & 63, w = tid >> 6;
    int wr = w >> 1, wc = w & 1;
    int l15 = l & 15, lg = l >> 4;
    int row0 = blockIdx.y * 128, col0 = blockIdx.x * 128;

    // staging geometry: instr i, wave w, lane l covers LDS bytes
    // ((i*4+w)*64+l)*16 linearly = row r = (i*4+w)*8 + (l>>3), k-col (l&7)*8
    int rsub = (l >> 3);
    int kq_  = (l & 7) * 8;

    const f32x4 zero4 = {0.f, 0.f, 0.f, 0.f};
    f32x4 acc[4][4];
    #pragma unroll
    for (int m = 0; m < 4; ++m)
        #pragma unroll
        for (int n = 0; n < 4; ++n) acc[m][n] = zero4;

    for (int k0 = 0; k0 < K; k0 += 64) {
        const short* Abase = A  + (size_t)row0 * K + k0;
        const short* Bbase = BT + (size_t)col0 * K + k0;
        #pragma unroll
        for (int i = 0; i < 4; ++i) {
            int r = i * 32 + w * 8 + rsub;
            gload16(Abase + (size_t)r * K + kq_, &As[(i * 4 + w) * 512]);
            gload16(Bbase + (size_t)r * K + kq_, &Bs[(i * 4 + w) * 512]);
        }
        __syncthreads();   // drains vmcnt(0) before any lane reads LDS

        #pragma unroll
        for (int ks = 0; ks < 2; ++ks) {
            short8v a[4], b[4];
            #pragma unroll
            for (int m = 0; m < 4; ++m)
                a[m] = *(const short8v*)&As[(wr * 64 + m * 16 + l15) * 64 + ks * 32 + lg * 8];
            #pragma unroll
            for (int n = 0; n < 4; ++n)
                b[n] = *(const short8v*)&Bs[(wc * 64 + n * 16 + l15) * 64 + ks * 32 + lg * 8];
            __builtin_amdgcn_s_setprio(1);
            #pragma unroll
            for (int m = 0; m < 4; ++m)
                #pragma unroll
                for (int n = 0; n < 4; ++n)
                    acc[m][n] = __builtin_amdgcn_mfma_f32_16x16x32_bf16(a[m], b[n], acc[m][n], 0, 0, 0);
            __builtin_amdgcn_s_setprio(0);
        }
        __syncthreads();
    }

    #pragma unroll
    for (int n = 0; n < 4; ++n) {
        int col = col0 + wc * 64 + n * 16 + l15;
        float bv = bias[col];
        #pragma unroll
        for (int m = 0; m < 4; ++m) {
            #pragma unroll
            for (int i = 0; i < 4; ++i) {
                int row = row0 + wr * 64 + m * 16 + lg * 4 + i;
                size_t off = (size_t)row * N + col;
                float v = acc[m][n][i] + bv;
                if (RESID) v += resid[off];
                if (GELU)  v = 0.5f * v * (1.0f + erff(v * 0.70710678118654752f));
                if (OUTBF) Cb[off] = f2bf(v);
                else       Cf[off] = v;
            }
        }
    }
}

// ---------------------------------------------------------------------------
// Flash attention, swapped-operand MFMA + key-permuted QK^T.
// Block = 128 q-rows of one (b,h); 4 waves x 32 q (2 q-frags).
// QK^T swapped & key-permuted: mfma kf reads K row
//   kappa(kf,l15) = (kf>>1)*32 + (l15>>2)*8 + (kf&1)*4 + (l15&3)
// so that lane (q,lg) ends up holding P for keys {ks*32+lg*8 .. +7} — which is
// exactly the PV B-fragment. P goes MFMA->regs->cvt_pk->MFMA, no LDS, no
// cross-lane. Softmax is key-order invariant. V reads unchanged (true keys).
// ---------------------------------------------------------------------------
__global__ __launch_bounds__(256) void fattn_bf16(const short* __restrict__ qkvb,
                                                  const short* __restrict__ vtg,
                                                  short* __restrict__ attnout) {
    __shared__ short Ks[2][64][72];
    __shared__ short Vt[2][64][72];

    int tid = threadIdx.x;
    int l = tid & 63, w = tid >> 6;
    int l15 = l & 15, lg = l >> 4;
    int qt = blockIdx.x, bh = blockIdx.y;
    int b = bh >> 3, h = bh & 7;
    int n0 = qt * 128;
    int qb = w * 32;
    const float kScale = 0.18033688011112042f;  // (1/8) * log2(e)
    int prow = ((l15 >> 2) << 3) + (l15 & 3);   // key-perm base for aK reads

    // Q b-fragments in registers (held for whole kernel)
    short8v bQ[2][2];
    #pragma unroll
    for (int qi = 0; qi < 2; ++qi)
        #pragma unroll
        for (int ks = 0; ks < 2; ++ks)
            bQ[qi][ks] = *(const short8v*)
                &qkvb[(size_t)(b * N_ + n0 + qb + qi * 16 + l15) * 1536 + h * 64 + ks * 32 + lg * 8];

    const f32x4 zero4 = {0.f, 0.f, 0.f, 0.f};
    f32x4 o[2][4];
    float m_run[2], l_run[2];
    #pragma unroll
    for (int qi = 0; qi < 2; ++qi) {
        m_run[qi] = -3.402823466e+38f;
        l_run[qi] = 0.f;
        #pragma unroll
        for (int df = 0; df < 4; ++df) o[qi][df] = zero4;
    }

    // staging geometry: 256 threads x 2 chunks cover a 64x64 bf16 tile
    int sr0 = tid >> 3, scq = (tid & 7) * 8;
    int sr1 = (tid + 256) >> 3;
    short8v kreg[2], vreg[2];

    // prologue: stage tile 0
    {
        kreg[0] = *(const short8v*)&qkvb[(size_t)(b * N_ + sr0) * 1536 + 512 + h * 64 + scq];
        kreg[1] = *(const short8v*)&qkvb[(size_t)(b * N_ + sr1) * 1536 + 512 + h * 64 + scq];
        vreg[0] = *(const short8v*)&vtg[((size_t)bh * 64 + sr0) * N_ + scq];
        vreg[1] = *(const short8v*)&vtg[((size_t)bh * 64 + sr1) * N_ + scq];
        *(short8v*)&Ks[0][sr0][scq] = kreg[0];
        *(short8v*)&Ks[0][sr1][scq] = kreg[1];
        *(short8v*)&Vt[0][sr0][scq] = vreg[0];
        *(short8v*)&Vt[0][sr1][scq] = vreg[1];
    }
    __syncthreads();

    int cur = 0;
    for (int kt = 0; kt < 32; ++kt) {
        // issue next tile's global loads (overlap with compute)
        if (kt < 31) {
            int kn = (kt + 1) * 64;
            kreg[0] = *(const short8v*)&qkvb[(size_t)(b * N_ + kn + sr0) * 1536 + 512 + h * 64 + scq];
            kreg[1] = *(const short8v*)&qkvb[(size_t)(b * N_ + kn + sr1) * 1536 + 512 + h * 64 + scq];
            vreg[0] = *(const short8v*)&vtg[((size_t)bh * 64 + sr0) * N_ + kn + scq];
            vreg[1] = *(const short8v*)&vtg[((size_t)bh * 64 + sr1) * N_ + kn + scq];
        }

        // ---- QK^T (swapped, key-permuted)
        // s[qi][kf][i] = S'[key = (kf>>1)*32 + lg*8 + (kf&1)*4 + i][q = l15]
        f32x4 s[2][4];
        #pragma unroll
        for (int kf = 0; kf < 4; ++kf) {
            int krow = ((kf >> 1) << 5) + ((kf & 1) << 2) + prow;
            short8v aK0 = *(const short8v*)&Ks[cur][krow][lg * 8];
            short8v aK1 = *(const short8v*)&Ks[cur][krow][32 + lg * 8];
            __builtin_amdgcn_s_setprio(1);
            #pragma unroll
            for (int qi = 0; qi < 2; ++qi) {
                s[qi][kf] = __builtin_amdgcn_mfma_f32_16x16x32_bf16(aK0, bQ[qi][0], zero4, 0, 0, 0);
                s[qi][kf] = __builtin_amdgcn_mfma_f32_16x16x32_bf16(aK1, bQ[qi][1], s[qi][kf], 0, 0, 0);
            }
            __builtin_amdgcn_s_setprio(0);
        }

        // ---- online softmax + direct pack into PV B-fragments
        short8v bP[2][2];
        #pragma unroll
        for (int qi = 0; qi < 2; ++qi) {
            float t0 = fmaxf(fmaxf(s[qi][0][0], s[qi][0][1]), fmaxf(s[qi][0][2], s[qi][0][3]));
            float t1 = fmaxf(fmaxf(s[qi][1][0], s[qi][1][1]), fmaxf(s[qi][1][2], s[qi][1][3]));
            float t2 = fmaxf(fmaxf(s[qi][2][0], s[qi][2][1]), fmaxf(s[qi][2][2], s[qi][2][3]));
            float t3 = fmaxf(fmaxf(s[qi][3][0], s[qi][3][1]), fmaxf(s[qi][3][2], s[qi][3][3]));
            float tm = fmaxf(fmaxf(t0, t1), fmaxf(t2, t3));
            tm = fmaxf(tm, __shfl_xor(tm, 16, 64));
            tm = fmaxf(tm, __shfl_xor(tm, 32, 64));
            float mnew = fmaxf(m_run[qi], tm);
            float scl = exp2f((m_run[qi] - mnew) * kScale);
            m_run[qi] = mnew;
            float nmk = -mnew * kScale;
            float ps = 0.f;
            #pragma unroll
            for (int kf = 0; kf < 4; ++kf) {
                #pragma unroll
                for (int i = 0; i < 4; ++i) {
                    float p = exp2f(fmaf(s[qi][kf][i], kScale, nmk));
                    s[qi][kf][i] = p;
                    ps += p;
                }
            }
            ps += __shfl_xor(ps, 16, 64);
            ps += __shfl_xor(ps, 32, 64);
            l_run[qi] = l_run[qi] * scl + ps;
            #pragma unroll
            for (int df = 0; df < 4; ++df) o[qi][df] *= scl;

            #pragma unroll
            for (int ks = 0; ks < 2; ++ks) {
                uint4v u;
                u[0] = cvtpk_bf16(s[qi][2 * ks][0],     s[qi][2 * ks][1]);
                u[1] = cvtpk_bf16(s[qi][2 * ks][2],     s[qi][2 * ks][3]);
                u[2] = cvtpk_bf16(s[qi][2 * ks + 1][0], s[qi][2 * ks + 1][1]);
                u[3] = cvtpk_bf16(s[qi][2 * ks + 1][2], s[qi][2 * ks + 1][3]);
                bP[qi][ks] = __builtin_bit_cast(short8v, u);
            }
        }

        // ---- PV (swapped): O'[d][q] += V^T[d][k] * P[k][q]
        #pragma unroll
        for (int df = 0; df < 4; ++df) {
            short8v aV0 = *(const short8v*)&Vt[cur][df * 16 + l15][lg * 8];
            short8v aV1 = *(const short8v*)&Vt[cur][df * 16 + l15][32 + lg * 8];
            __builtin_amdgcn_s_setprio(1);
            #pragma unroll
            for (int qi = 0; qi < 2; ++qi) {
                o[qi][df] = __builtin_amdgcn_mfma_f32_16x16x32_bf16(aV0, bP[qi][0], o[qi][df], 0, 0, 0);
                o[qi][df] = __builtin_amdgcn_mfma_f32_16x16x32_bf16(aV1, bP[qi][1], o[qi][df], 0, 0, 0);
            }
            __builtin_amdgcn_s_setprio(0);
        }

        // write next tile into the other buffer; single barrier per iteration
        if (kt < 31) {
            *(short8v*)&Ks[cur ^ 1][sr0][scq] = kreg[0];
            *(short8v*)&Ks[cur ^ 1][sr1][scq] = kreg[1];
            *(short8v*)&Vt[cur ^ 1][sr0][scq] = vreg[0];
            *(short8v*)&Vt[cur ^ 1][sr1][scq] = vreg[1];
        }
        __syncthreads();
        cur ^= 1;
    }

    // epilogue: normalize and store (4 consecutive d per packed 8B store)
    #pragma unroll
    for (int qi = 0; qi < 2; ++qi) {
        float linv = 1.0f / l_run[qi];
        size_t rowb = (size_t)(b * N_ + n0 + qb + qi * 16 + l15) * D_ + h * 64;
        #pragma unroll
        for (int df = 0; df < 4; ++df) {
            uint2 uu;
            uu.x = cvtpk_bf16(o[qi][df][0] * linv, o[qi][df][1] * linv);
            uu.y = cvtpk_bf16(o[qi][df][2] * linv, o[qi][df][3] * linv);
            *(uint2*)&attnout[rowb + df * 16 + lg * 4] = uu;
        }
    }
}

// ---------------------------------------------------------------------------
extern "C" void kernel_launch(void* const* d_in, const int* in_sizes, int n_in,
                              void* d_out, int out_size, void* d_ws, size_t ws_size,
                              hipStream_t stream) {
    const float* x      = (const float*)d_in[0];
    const float* ln1_g  = (const float*)d_in[1];
    const float* ln1_b  = (const float*)d_in[2];
    const float* Wqkv   = (const float*)d_in[3];
    const float* bqkv   = (const float*)d_in[4];
    const float* Wproj  = (const float*)d_in[5];
    const float* bproj  = (const float*)d_in[6];
    const float* ln2_g  = (const float*)d_in[7];
    const float* ln2_b  = (const float*)d_in[8];
    const float* W1     = (const float*)d_in[9];
    const float* b1     = (const float*)d_in[10];
    const float* W2     = (const float*)d_in[11];
    const float* b2     = (const float*)d_in[12];
    float* out = (float*)d_out;

    char* ws = (char*)d_ws;
    short* h_bf    = (short*)(ws + (size_t)0);
    short* qkv_bf  = (short*)(ws + ((size_t)8  << 20));
    short* vtg     = (short*)(ws + ((size_t)32 << 20));
    short* attn_bf = (short*)(ws + ((size_t)40 << 20));
    float* x2      = (float*)(ws + ((size_t)48 << 20));
    short* h2_bf   = (short*)(ws + ((size_t)64 << 20));
    short* ffh_bf  = (short*)(ws + ((size_t)72 << 20));
    short* WTqkv   = (short*)(ws + ((size_t)104 << 20));
    short* WTproj  = (short*)(ws + ((size_t)106 << 20));
    short* WT1     = (short*)(ws + ((size_t)108 << 20));
    short* WT2     = (short*)(ws + ((size_t)110 << 20));

    dim3 blk(256);

    // weight transposes (bf16)
    wt_kernel<<<dim3(24, 8),  blk, 0, stream>>>(Wqkv,  WTqkv,  512,  1536);
    wt_kernel<<<dim3(8, 8),   blk, 0, stream>>>(Wproj, WTproj, 512,  512);
    wt_kernel<<<dim3(32, 8),  blk, 0, stream>>>(W1,    WT1,    512,  2048);
    wt_kernel<<<dim3(8, 32),  blk, 0, stream>>>(W2,    WT2,    2048, 512);

    // 1. h = LN1(x)  (bf16)
    ln_bf16_kernel<<<ROWS_ / 4, blk, 0, stream>>>(x, ln1_g, ln1_b, h_bf);

    // 2. qkv = h @ Wqkv + bqkv  (bf16 out)
    gemm_bf16<false, false, true><<<dim3(12, 64), blk, 0, stream>>>(
        h_bf, WTqkv, bqkv, nullptr, nullptr, qkv_bf, ROWS_, 1536, 512);

    // 3a. V transpose per head
    vt_kernel<<<dim3(32, 32), blk, 0, stream>>>(qkv_bf, vtg);

    // 3b. attention (bf16 out)
    fattn_bf16<<<dim3(16, 32), blk, 0, stream>>>(qkv_bf, vtg, attn_bf);

    // 4. x2 = x + attn @ Wproj + bproj  (fp32 out)
    gemm_bf16<false, true, false><<<dim3(4, 64), blk, 0, stream>>>(
        attn_bf, WTproj, bproj, x, x2, nullptr, ROWS_, 512, 512);

    // 5. h2 = LN2(x2)  (bf16)
    ln_bf16_kernel<<<ROWS_ / 4, blk, 0, stream>>>(x2, ln2_g, ln2_b, h2_bf);

    // 6. ffh = gelu(h2 @ W1 + b1)  (bf16 out)
    gemm_bf16<true, false, true><<<dim3(16, 64), blk, 0, stream>>>(
        h2_bf, WT1, b1, nullptr, nullptr, ffh_bf, ROWS_, 2048, 512);

    // 7. out = x2 + ffh @ W2 + b2  (fp32 out)
    gemm_bf16<false, true, false><<<dim3(4, 64), blk, 0, stream>>>(
        ffh_bf, WT2, b2, x2, out, nullptr, ROWS_, 512, 2048);
}

// Round 6
// 237.625 us; speedup vs baseline: 1.0314x; 1.0314x over previous
//
#include <hip/hip_runtime.h>

#define B_ 4
#define N_ 2048
#define D_ 512
#define H_ 8
#define DH_ 64
#define ROWS_ 8192

typedef float f32x4 __attribute__((ext_vector_type(4)));
typedef short short8v __attribute__((ext_vector_type(8)));
typedef short short4v __attribute__((ext_vector_type(4)));
typedef unsigned uint4v __attribute__((ext_vector_type(4)));

__device__ __forceinline__ short f2bf(float f) {
    unsigned u = __builtin_bit_cast(unsigned, f);
    u += 0x7FFFu + ((u >> 16) & 1u);   // round-to-nearest-even
    return (short)(u >> 16);
}

__device__ __forceinline__ unsigned cvtpk_bf16(float lo, float hi) {
    unsigned r;
    asm("v_cvt_pk_bf16_f32 %0, %1, %2" : "=v"(r) : "v"(lo), "v"(hi));
    return r;
}

// async global->LDS, 16B per lane; lds dest is wave-uniform base + lane*16.
__device__ __forceinline__ void gload16(const void* g, void* l) {
    __builtin_amdgcn_global_load_lds(
        (const __attribute__((address_space(1))) unsigned int*)g,
        (__attribute__((address_space(3))) unsigned int*)l, 16, 0, 0);
}

// ---------------------------------------------------------------------------
// LayerNorm fp32-in -> bf16-out. One wave per row of 512; 4 rows/block.
// ---------------------------------------------------------------------------
__global__ __launch_bounds__(256) void ln_bf16_kernel(const float* __restrict__ x,
                                                      const float* __restrict__ g,
                                                      const float* __restrict__ bb,
                                                      short* __restrict__ out) {
    int wave = threadIdx.x >> 6;
    int lane = threadIdx.x & 63;
    int row  = blockIdx.x * 4 + wave;
    const float* xr = x + (size_t)row * D_;

    float4 v0 = ((const float4*)xr)[lane * 2 + 0];
    float4 v1 = ((const float4*)xr)[lane * 2 + 1];

    float s = v0.x + v0.y + v0.z + v0.w + v1.x + v1.y + v1.z + v1.w;
    #pragma unroll
    for (int off = 32; off; off >>= 1) s += __shfl_xor(s, off, 64);
    float mu = s * (1.0f / D_);

    float d0 = v0.x - mu, d1 = v0.y - mu, d2 = v0.z - mu, d3 = v0.w - mu;
    float d4 = v1.x - mu, d5 = v1.y - mu, d6 = v1.z - mu, d7 = v1.w - mu;
    float vs = d0*d0 + d1*d1 + d2*d2 + d3*d3 + d4*d4 + d5*d5 + d6*d6 + d7*d7;
    #pragma unroll
    for (int off = 32; off; off >>= 1) vs += __shfl_xor(vs, off, 64);
    float rstd = rsqrtf(vs * (1.0f / D_) + 1e-5f);

    float4 g0 = ((const float4*)g)[lane * 2 + 0];
    float4 g1 = ((const float4*)g)[lane * 2 + 1];
    float4 b0 = ((const float4*)bb)[lane * 2 + 0];
    float4 b1 = ((const float4*)bb)[lane * 2 + 1];

    short8v ov;
    ov[0] = f2bf(d0 * rstd * g0.x + b0.x);
    ov[1] = f2bf(d1 * rstd * g0.y + b0.y);
    ov[2] = f2bf(d2 * rstd * g0.z + b0.z);
    ov[3] = f2bf(d3 * rstd * g0.w + b0.w);
    ov[4] = f2bf(d4 * rstd * g1.x + b1.x);
    ov[5] = f2bf(d5 * rstd * g1.y + b1.y);
    ov[6] = f2bf(d6 * rstd * g1.z + b1.z);
    ov[7] = f2bf(d7 * rstd * g1.w + b1.w);
    *(short8v*)&out[(size_t)row * D_ + lane * 8] = ov;
}

// ---------------------------------------------------------------------------
// Weight transpose + cvt: W[K][N] fp32 -> WT[N][K] bf16. 64x64 tile per block.
// ---------------------------------------------------------------------------
__global__ __launch_bounds__(256) void wt_kernel(const float* __restrict__ W,
                                                 short* __restrict__ WT,
                                                 int K, int N) {
    __shared__ short Ts[64][72];
    int tid = threadIdx.x;
    int n0 = blockIdx.x * 64, k0 = blockIdx.y * 64;

    #pragma unroll
    for (int i = 0; i < 4; ++i) {
        int idx = tid + i * 256;            // 1024 float4 chunks
        int k = idx >> 4, nq = (idx & 15) * 4;
        float4 wv = *(const float4*)&W[(size_t)(k0 + k) * N + n0 + nq];
        short4v t;
        t[0] = f2bf(wv.x); t[1] = f2bf(wv.y); t[2] = f2bf(wv.z); t[3] = f2bf(wv.w);
        *(short4v*)&Ts[k][nq] = t;
    }
    __syncthreads();

    int n = tid >> 2, kq = (tid & 3) * 16;
    short8v o0, o1;
    #pragma unroll
    for (int j = 0; j < 8; ++j) { o0[j] = Ts[kq + j][n]; o1[j] = Ts[kq + 8 + j][n]; }
    *(short8v*)&WT[(size_t)(n0 + n) * K + k0 + kq]     = o0;
    *(short8v*)&WT[(size_t)(n0 + n) * K + k0 + kq + 8] = o1;
}

// ---------------------------------------------------------------------------
// V transpose per head: qkv_bf[row][1536] (v at +1024) -> vtg[bh][64 d][2048 n]
// ---------------------------------------------------------------------------
__global__ __launch_bounds__(256) void vt_kernel(const short* __restrict__ qkvb,
                                                 short* __restrict__ vtg) {
    __shared__ short Ts[64][72];
    int tid = threadIdx.x;
    int n0 = blockIdx.x * 64;
    int bh = blockIdx.y;
    int b = bh >> 3, h = bh & 7;

    #pragma unroll
    for (int i = 0; i < 2; ++i) {
        int idx = tid + i * 256;            // 512 chunks of 8 bf16
        int n = idx >> 3, dq = (idx & 7) * 8;
        *(short8v*)&Ts[n][dq] =
            *(const short8v*)&qkvb[(size_t)(b * N_ + n0 + n) * 1536 + 1024 + h * 64 + dq];
    }
    __syncthreads();

    int d = tid >> 2, nq = (tid & 3) * 16;
    short8v o0, o1;
    #pragma unroll
    for (int j = 0; j < 8; ++j) { o0[j] = Ts[nq + j][d]; o1[j] = Ts[nq + 8 + j][d]; }
    size_t base = ((size_t)bh * 64 + d) * N_ + n0 + nq;
    *(short8v*)&vtg[base]     = o0;
    *(short8v*)&vtg[base + 8] = o1;
}

// ---------------------------------------------------------------------------
// bf16 MFMA GEMM, m97 structure + T2 both-sides XOR swizzle.
// 128xBN tile (BN=128 or 64), BK=64, global_load_lds width-16 into LINEAR
// LDS with pre-swizzled global source; fragment reads apply the same XOR.
// 4 waves: 2x2, wave tile 64 x (BN/2).
// ---------------------------------------------------------------------------
template<int BN, bool GELU, bool RESID, bool OUTBF>
__global__ __launch_bounds__(256) void gemm_bf16(const short* __restrict__ A,
                                                 const short* __restrict__ BT,
                                                 const float* __restrict__ bias,
                                                 const float* __restrict__ resid,
                                                 float* __restrict__ Cf,
                                                 short* __restrict__ Cb,
                                                 int M, int N, int K) {
    constexpr int WCW = BN / 2;      // wave col width
    constexpr int NF  = WCW / 16;    // B fragments per wave
    __shared__ short As[128 * 64];
    __shared__ short Bs[BN * 64];
    int tid = threadIdx.x;
    int l = tid & 63, w = tid >> 6;
    int wr = w >> 1, wc = w & 1;
    int l15 = l & 15, lg = l >> 4;
    int row0 = blockIdx.y * 128, col0 = blockIdx.x * BN;

    // staging: lane l covers LDS row (chunk*8 + (l>>3)), slot (l&7).
    // source col slot pre-swizzled so LDS[r][s] = global[r][s ^ (r&7)].
    int rsub = l >> 3;
    int kq_  = ((l & 7) ^ rsub) * 8;
    int rsw  = l15 & 7;              // read-side row swizzle

    const f32x4 zero4 = {0.f, 0.f, 0.f, 0.f};
    f32x4 acc[4][NF];
    #pragma unroll
    for (int m = 0; m < 4; ++m)
        #pragma unroll
        for (int n = 0; n < NF; ++n) acc[m][n] = zero4;

    for (int k0 = 0; k0 < K; k0 += 64) {
        const short* Abase = A  + (size_t)row0 * K + k0;
        const short* Bbase = BT + (size_t)col0 * K + k0;
        #pragma unroll
        for (int i = 0; i < 4; ++i) {
            int r = i * 32 + w * 8 + rsub;
            gload16(Abase + (size_t)r * K + kq_, &As[(i * 4 + w) * 512]);
        }
        #pragma unroll
        for (int i = 0; i < BN / 32; ++i) {
            int r = i * 32 + w * 8 + rsub;
            gload16(Bbase + (size_t)r * K + kq_, &Bs[(i * 4 + w) * 512]);
        }
        __syncthreads();   // drains vmcnt(0) before any lane reads LDS

        #pragma unroll
        for (int ks = 0; ks < 2; ++ks) {
            int slot = ((ks * 4 + lg) ^ rsw) * 8;
            short8v a[4], b[NF];
            #pragma unroll
            for (int m = 0; m < 4; ++m)
                a[m] = *(const short8v*)&As[(wr * 64 + m * 16 + l15) * 64 + slot];
            #pragma unroll
            for (int n = 0; n < NF; ++n)
                b[n] = *(const short8v*)&Bs[(wc * WCW + n * 16 + l15) * 64 + slot];
            __builtin_amdgcn_s_setprio(1);
            #pragma unroll
            for (int m = 0; m < 4; ++m)
                #pragma unroll
                for (int n = 0; n < NF; ++n)
                    acc[m][n] = __builtin_amdgcn_mfma_f32_16x16x32_bf16(a[m], b[n], acc[m][n], 0, 0, 0);
            __builtin_amdgcn_s_setprio(0);
        }
        __syncthreads();
    }

    #pragma unroll
    for (int n = 0; n < NF; ++n) {
        int col = col0 + wc * WCW + n * 16 + l15;
        float bv = bias[col];
        #pragma unroll
        for (int m = 0; m < 4; ++m) {
            #pragma unroll
            for (int i = 0; i < 4; ++i) {
                int row = row0 + wr * 64 + m * 16 + lg * 4 + i;
                size_t off = (size_t)row * N + col;
                float v = acc[m][n][i] + bv;
                if (RESID) v += resid[off];
                if (GELU)  v = 0.5f * v * (1.0f + erff(v * 0.70710678118654752f));
                if (OUTBF) Cb[off] = f2bf(v);
                else       Cf[off] = v;
            }
        }
    }
}

// ---------------------------------------------------------------------------
// Flash attention, swapped-operand MFMA + key-permuted QK^T, 8 waves.
// Block = 128 q-rows of one (b,h); 8 waves x 16 q-rows each.
// QK^T swapped & key-permuted so each lane's P is directly the PV B-fragment
// (MFMA->regs->cvt_pk->MFMA, no P LDS, no cross-lane). Defer-max (THR=8).
// ---------------------------------------------------------------------------
__global__ __launch_bounds__(512) void fattn_bf16(const short* __restrict__ qkvb,
                                                  const short* __restrict__ vtg,
                                                  short* __restrict__ attnout) {
    __shared__ short Ks[2][64][68];
    __shared__ short Vt[2][64][68];

    int tid = threadIdx.x;
    int l = tid & 63, w = tid >> 6;          // 8 waves
    int l15 = l & 15, lg = l >> 4;
    int qt = blockIdx.x, bh = blockIdx.y;
    int b = bh >> 3, h = bh & 7;
    int n0 = qt * 128;
    int qb = w * 16;
    const float kScale = 0.18033688011112042f;  // (1/8) * log2(e)
    const float kThr   = 44.361420f;            // 8 / kScale
    int prow = ((l15 >> 2) << 3) + (l15 & 3);   // key-perm base for aK reads

    // Q b-fragments in registers (held for whole kernel)
    short8v bQ[2];
    #pragma unroll
    for (int ks = 0; ks < 2; ++ks)
        bQ[ks] = *(const short8v*)
            &qkvb[(size_t)(b * N_ + n0 + qb + l15) * 1536 + h * 64 + ks * 32 + lg * 8];

    const f32x4 zero4 = {0.f, 0.f, 0.f, 0.f};
    f32x4 o[4];
    float m_run = -3.402823466e+38f, l_run = 0.f;
    #pragma unroll
    for (int df = 0; df < 4; ++df) o[df] = zero4;

    // staging: 512 threads x 1 chunk of 8 shorts covers a 64x64 tile
    int sr = tid >> 3, scq = (tid & 7) * 8;
    short8v kreg, vreg;

    // prologue: stage tile 0
    kreg = *(const short8v*)&qkvb[(size_t)(b * N_ + sr) * 1536 + 512 + h * 64 + scq];
    vreg = *(const short8v*)&vtg[((size_t)bh * 64 + sr) * N_ + scq];
    *(short8v*)&Ks[0][sr][scq] = kreg;
    *(short8v*)&Vt[0][sr][scq] = vreg;
    __syncthreads();

    int cur = 0;
    for (int kt = 0; kt < 32; ++kt) {
        // issue next tile's global loads (overlap with compute)
        if (kt < 31) {
            int kn = (kt + 1) * 64;
            kreg = *(const short8v*)&qkvb[(size_t)(b * N_ + kn + sr) * 1536 + 512 + h * 64 + scq];
            vreg = *(const short8v*)&vtg[((size_t)bh * 64 + sr) * N_ + kn + scq];
        }

        // ---- QK^T (swapped, key-permuted)
        f32x4 s[4];
        #pragma unroll
        for (int kf = 0; kf < 4; ++kf) {
            int krow = ((kf >> 1) << 5) + ((kf & 1) << 2) + prow;
            short8v aK0 = *(const short8v*)&Ks[cur][krow][lg * 8];
            short8v aK1 = *(const short8v*)&Ks[cur][krow][32 + lg * 8];
            __builtin_amdgcn_s_setprio(1);
            s[kf] = __builtin_amdgcn_mfma_f32_16x16x32_bf16(aK0, bQ[0], zero4, 0, 0, 0);
            s[kf] = __builtin_amdgcn_mfma_f32_16x16x32_bf16(aK1, bQ[1], s[kf], 0, 0, 0);
            __builtin_amdgcn_s_setprio(0);
        }

        // ---- online softmax with defer-max; direct pack into PV B-fragment
        short8v bP[2];
        {
            float t0 = fmaxf(fmaxf(s[0][0], s[0][1]), fmaxf(s[0][2], s[0][3]));
            float t1 = fmaxf(fmaxf(s[1][0], s[1][1]), fmaxf(s[1][2], s[1][3]));
            float t2 = fmaxf(fmaxf(s[2][0], s[2][1]), fmaxf(s[2][2], s[2][3]));
            float t3 = fmaxf(fmaxf(s[3][0], s[3][1]), fmaxf(s[3][2], s[3][3]));
            float tm = fmaxf(fmaxf(t0, t1), fmaxf(t2, t3));
            tm = fmaxf(tm, __shfl_xor(tm, 16, 64));
            tm = fmaxf(tm, __shfl_xor(tm, 32, 64));
            bool defer = __all(tm <= m_run + kThr);
            float scl = 1.0f;
            if (!defer) {
                float mnew = fmaxf(m_run, tm);
                scl = exp2f((m_run - mnew) * kScale);
                m_run = mnew;
            }
            float nmk = -m_run * kScale;
            float ps = 0.f;
            #pragma unroll
            for (int kf = 0; kf < 4; ++kf) {
                #pragma unroll
                for (int i = 0; i < 4; ++i) {
                    float p = exp2f(fmaf(s[kf][i], kScale, nmk));
                    s[kf][i] = p;
                    ps += p;
                }
            }
            ps += __shfl_xor(ps, 16, 64);
            ps += __shfl_xor(ps, 32, 64);
            if (defer) {
                l_run += ps;
            } else {
                l_run = l_run * scl + ps;
                #pragma unroll
                for (int df = 0; df < 4; ++df) o[df] *= scl;
            }
            #pragma unroll
            for (int ks = 0; ks < 2; ++ks) {
                uint4v u;
                u[0] = cvtpk_bf16(s[2 * ks][0],     s[2 * ks][1]);
                u[1] = cvtpk_bf16(s[2 * ks][2],     s[2 * ks][3]);
                u[2] = cvtpk_bf16(s[2 * ks + 1][0], s[2 * ks + 1][1]);
                u[3] = cvtpk_bf16(s[2 * ks + 1][2], s[2 * ks + 1][3]);
                bP[ks] = __builtin_bit_cast(short8v, u);
            }
        }

        // ---- PV (swapped): O'[d][q] += V^T[d][k] * P[k][q]
        #pragma unroll
        for (int df = 0; df < 4; ++df) {
            short8v aV0 = *(const short8v*)&Vt[cur][df * 16 + l15][lg * 8];
            short8v aV1 = *(const short8v*)&Vt[cur][df * 16 + l15][32 + lg * 8];
            __builtin_amdgcn_s_setprio(1);
            o[df] = __builtin_amdgcn_mfma_f32_16x16x32_bf16(aV0, bP[0], o[df], 0, 0, 0);
            o[df] = __builtin_amdgcn_mfma_f32_16x16x32_bf16(aV1, bP[1], o[df], 0, 0, 0);
            __builtin_amdgcn_s_setprio(0);
        }

        // write next tile into the other buffer; single barrier per iteration
        if (kt < 31) {
            *(short8v*)&Ks[cur ^ 1][sr][scq] = kreg;
            *(short8v*)&Vt[cur ^ 1][sr][scq] = vreg;
        }
        __syncthreads();
        cur ^= 1;
    }

    // epilogue: normalize and store (4 consecutive d per packed 8B store)
    {
        float linv = 1.0f / l_run;
        size_t rowb = (size_t)(b * N_ + n0 + qb + l15) * D_ + h * 64;
        #pragma unroll
        for (int df = 0; df < 4; ++df) {
            uint2 uu;
            uu.x = cvtpk_bf16(o[df][0] * linv, o[df][1] * linv);
            uu.y = cvtpk_bf16(o[df][2] * linv, o[df][3] * linv);
            *(uint2*)&attnout[rowb + df * 16 + lg * 4] = uu;
        }
    }
}

// ---------------------------------------------------------------------------
extern "C" void kernel_launch(void* const* d_in, const int* in_sizes, int n_in,
                              void* d_out, int out_size, void* d_ws, size_t ws_size,
                              hipStream_t stream) {
    const float* x      = (const float*)d_in[0];
    const float* ln1_g  = (const float*)d_in[1];
    const float* ln1_b  = (const float*)d_in[2];
    const float* Wqkv   = (const float*)d_in[3];
    const float* bqkv   = (const float*)d_in[4];
    const float* Wproj  = (const float*)d_in[5];
    const float* bproj  = (const float*)d_in[6];
    const float* ln2_g  = (const float*)d_in[7];
    const float* ln2_b  = (const float*)d_in[8];
    const float* W1     = (const float*)d_in[9];
    const float* b1     = (const float*)d_in[10];
    const float* W2     = (const float*)d_in[11];
    const float* b2     = (const float*)d_in[12];
    float* out = (float*)d_out;

    char* ws = (char*)d_ws;
    short* h_bf    = (short*)(ws + (size_t)0);
    short* qkv_bf  = (short*)(ws + ((size_t)8  << 20));
    short* vtg     = (short*)(ws + ((size_t)32 << 20));
    short* attn_bf = (short*)(ws + ((size_t)40 << 20));
    float* x2      = (float*)(ws + ((size_t)48 << 20));
    short* h2_bf   = (short*)(ws + ((size_t)64 << 20));
    short* ffh_bf  = (short*)(ws + ((size_t)72 << 20));
    short* WTqkv   = (short*)(ws + ((size_t)104 << 20));
    short* WTproj  = (short*)(ws + ((size_t)106 << 20));
    short* WT1     = (short*)(ws + ((size_t)108 << 20));
    short* WT2     = (short*)(ws + ((size_t)110 << 20));

    dim3 blk(256);

    // weight transposes (bf16)
    wt_kernel<<<dim3(24, 8),  blk, 0, stream>>>(Wqkv,  WTqkv,  512,  1536);
    wt_kernel<<<dim3(8, 8),   blk, 0, stream>>>(Wproj, WTproj, 512,  512);
    wt_kernel<<<dim3(32, 8),  blk, 0, stream>>>(W1,    WT1,    512,  2048);
    wt_kernel<<<dim3(8, 32),  blk, 0, stream>>>(W2,    WT2,    2048, 512);

    // 1. h = LN1(x)  (bf16)
    ln_bf16_kernel<<<ROWS_ / 4, blk, 0, stream>>>(x, ln1_g, ln1_b, h_bf);

    // 2. qkv = h @ Wqkv + bqkv  (bf16 out)
    gemm_bf16<128, false, false, true><<<dim3(12, 64), blk, 0, stream>>>(
        h_bf, WTqkv, bqkv, nullptr, nullptr, qkv_bf, ROWS_, 1536, 512);

    // 3a. V transpose per head
    vt_kernel<<<dim3(32, 32), blk, 0, stream>>>(qkv_bf, vtg);

    // 3b. attention (bf16 out), 8 waves per block
    fattn_bf16<<<dim3(16, 32), dim3(512), 0, stream>>>(qkv_bf, vtg, attn_bf);

    // 4. x2 = x + attn @ Wproj + bproj  (fp32 out)  [BN=64 -> 512 blocks]
    gemm_bf16<64, false, true, false><<<dim3(8, 64), blk, 0, stream>>>(
        attn_bf, WTproj, bproj, x, x2, nullptr, ROWS_, 512, 512);

    // 5. h2 = LN2(x2)  (bf16)
    ln_bf16_kernel<<<ROWS_ / 4, blk, 0, stream>>>(x2, ln2_g, ln2_b, h2_bf);

    // 6. ffh = gelu(h2 @ W1 + b1)  (bf16 out)
    gemm_bf16<128, true, false, true><<<dim3(16, 64), blk, 0, stream>>>(
        h2_bf, WT1, b1, nullptr, nullptr, ffh_bf, ROWS_, 2048, 512);

    // 7. out = x2 + ffh @ W2 + b2  (fp32 out)  [BN=64 -> 512 blocks]
    gemm_bf16<64, false, true, false><<<dim3(8, 64), blk, 0, stream>>>(
        ffh_bf, WT2, b2, x2, out, nullptr, ROWS_, 512, 2048);
}

// Round 7
// 228.515 us; speedup vs baseline: 1.0725x; 1.0399x over previous
//
#include <hip/hip_runtime.h>

#define B_ 4
#define N_ 2048
#define D_ 512
#define H_ 8
#define DH_ 64
#define ROWS_ 8192

typedef float f32x4 __attribute__((ext_vector_type(4)));
typedef short short8v __attribute__((ext_vector_type(8)));
typedef short short4v __attribute__((ext_vector_type(4)));
typedef unsigned uint4v __attribute__((ext_vector_type(4)));

__device__ __forceinline__ short f2bf(float f) {
    unsigned u = __builtin_bit_cast(unsigned, f);
    u += 0x7FFFu + ((u >> 16) & 1u);   // round-to-nearest-even
    return (short)(u >> 16);
}

__device__ __forceinline__ unsigned cvtpk_bf16(float lo, float hi) {
    unsigned r;
    asm("v_cvt_pk_bf16_f32 %0, %1, %2" : "=v"(r) : "v"(lo), "v"(hi));
    return r;
}

// async global->LDS, 16B per lane; lds dest = wave-uniform base + lane*16.
__device__ __forceinline__ void gload16(const void* g, void* l) {
    __builtin_amdgcn_global_load_lds(
        (const __attribute__((address_space(1))) unsigned int*)g,
        (__attribute__((address_space(3))) unsigned int*)l, 16, 0, 0);
}

__device__ __forceinline__ void waitvm0_barrier() {
    asm volatile("s_waitcnt vmcnt(0)" ::: "memory");
    __builtin_amdgcn_s_barrier();
}

// ---------------------------------------------------------------------------
// LayerNorm fp32-in -> bf16-out. One wave per row of 512; 4 rows/block.
// ---------------------------------------------------------------------------
__global__ __launch_bounds__(256) void ln_bf16_kernel(const float* __restrict__ x,
                                                      const float* __restrict__ g,
                                                      const float* __restrict__ bb,
                                                      short* __restrict__ out) {
    int wave = threadIdx.x >> 6;
    int lane = threadIdx.x & 63;
    int row  = blockIdx.x * 4 + wave;
    const float* xr = x + (size_t)row * D_;

    float4 v0 = ((const float4*)xr)[lane * 2 + 0];
    float4 v1 = ((const float4*)xr)[lane * 2 + 1];

    float s = v0.x + v0.y + v0.z + v0.w + v1.x + v1.y + v1.z + v1.w;
    #pragma unroll
    for (int off = 32; off; off >>= 1) s += __shfl_xor(s, off, 64);
    float mu = s * (1.0f / D_);

    float d0 = v0.x - mu, d1 = v0.y - mu, d2 = v0.z - mu, d3 = v0.w - mu;
    float d4 = v1.x - mu, d5 = v1.y - mu, d6 = v1.z - mu, d7 = v1.w - mu;
    float vs = d0*d0 + d1*d1 + d2*d2 + d3*d3 + d4*d4 + d5*d5 + d6*d6 + d7*d7;
    #pragma unroll
    for (int off = 32; off; off >>= 1) vs += __shfl_xor(vs, off, 64);
    float rstd = rsqrtf(vs * (1.0f / D_) + 1e-5f);

    float4 g0 = ((const float4*)g)[lane * 2 + 0];
    float4 g1 = ((const float4*)g)[lane * 2 + 1];
    float4 b0 = ((const float4*)bb)[lane * 2 + 0];
    float4 b1 = ((const float4*)bb)[lane * 2 + 1];

    short8v ov;
    ov[0] = f2bf(d0 * rstd * g0.x + b0.x);
    ov[1] = f2bf(d1 * rstd * g0.y + b0.y);
    ov[2] = f2bf(d2 * rstd * g0.z + b0.z);
    ov[3] = f2bf(d3 * rstd * g0.w + b0.w);
    ov[4] = f2bf(d4 * rstd * g1.x + b1.x);
    ov[5] = f2bf(d5 * rstd * g1.y + b1.y);
    ov[6] = f2bf(d6 * rstd * g1.z + b1.z);
    ov[7] = f2bf(d7 * rstd * g1.w + b1.w);
    *(short8v*)&out[(size_t)row * D_ + lane * 8] = ov;
}

// ---------------------------------------------------------------------------
// Weight transpose + cvt: W[K][N] fp32 -> WT[N][K] bf16. 64x64 tile per block.
// ---------------------------------------------------------------------------
__global__ __launch_bounds__(256) void wt_kernel(const float* __restrict__ W,
                                                 short* __restrict__ WT,
                                                 int K, int N) {
    __shared__ short Ts[64][72];
    int tid = threadIdx.x;
    int n0 = blockIdx.x * 64, k0 = blockIdx.y * 64;

    #pragma unroll
    for (int i = 0; i < 4; ++i) {
        int idx = tid + i * 256;            // 1024 float4 chunks
        int k = idx >> 4, nq = (idx & 15) * 4;
        float4 wv = *(const float4*)&W[(size_t)(k0 + k) * N + n0 + nq];
        short4v t;
        t[0] = f2bf(wv.x); t[1] = f2bf(wv.y); t[2] = f2bf(wv.z); t[3] = f2bf(wv.w);
        *(short4v*)&Ts[k][nq] = t;
    }
    __syncthreads();

    int n = tid >> 2, kq = (tid & 3) * 16;
    short8v o0, o1;
    #pragma unroll
    for (int j = 0; j < 8; ++j) { o0[j] = Ts[kq + j][n]; o1[j] = Ts[kq + 8 + j][n]; }
    *(short8v*)&WT[(size_t)(n0 + n) * K + k0 + kq]     = o0;
    *(short8v*)&WT[(size_t)(n0 + n) * K + k0 + kq + 8] = o1;
}

// ---------------------------------------------------------------------------
// V transpose per head: qkv_bf[row][1536] (v at +1024) -> vtg[bh][64 d][2048 n]
// ---------------------------------------------------------------------------
__global__ __launch_bounds__(256) void vt_kernel(const short* __restrict__ qkvb,
                                                 short* __restrict__ vtg) {
    __shared__ short Ts[64][72];
    int tid = threadIdx.x;
    int n0 = blockIdx.x * 64;
    int bh = blockIdx.y;
    int b = bh >> 3, h = bh & 7;

    #pragma unroll
    for (int i = 0; i < 2; ++i) {
        int idx = tid + i * 256;            // 512 chunks of 8 bf16
        int n = idx >> 3, dq = (idx & 7) * 8;
        *(short8v*)&Ts[n][dq] =
            *(const short8v*)&qkvb[(size_t)(b * N_ + n0 + n) * 1536 + 1024 + h * 64 + dq];
    }
    __syncthreads();

    int d = tid >> 2, nq = (tid & 3) * 16;
    short8v o0, o1;
    #pragma unroll
    for (int j = 0; j < 8; ++j) { o0[j] = Ts[nq + j][d]; o1[j] = Ts[nq + 8 + j][d]; }
    size_t base = ((size_t)bh * 64 + d) * N_ + n0 + nq;
    *(short8v*)&vtg[base]     = o0;
    *(short8v*)&vtg[base + 8] = o1;
}

// ---------------------------------------------------------------------------
// bf16 MFMA GEMM: 128x64 tile, BK=64, DOUBLE-BUFFERED global_load_lds
// staging (2-phase: issue next tile, MFMA current, vmcnt(0)+barrier).
// Linear LDS + both-sides XOR swizzle (T2/rule21). 4 waves 2x2.
// ---------------------------------------------------------------------------
template<bool GELU, bool RESID, bool OUTBF>
__global__ __launch_bounds__(256) void gemm_bf16(const short* __restrict__ A,
                                                 const short* __restrict__ BT,
                                                 const float* __restrict__ bias,
                                                 const float* __restrict__ resid,
                                                 float* __restrict__ Cf,
                                                 short* __restrict__ Cb,
                                                 int M, int N, int K) {
    __shared__ short As[2][128 * 64];
    __shared__ short Bs[2][64 * 64];
    int tid = threadIdx.x;
    int l = tid & 63, w = tid >> 6;
    int wr = w >> 1, wc = w & 1;
    int l15 = l & 15, lg = l >> 4;
    int row0 = blockIdx.y * 128, col0 = blockIdx.x * 64;

    // staging: lane covers LDS row (group*8 + (l>>3)), slot (l&7);
    // global source col pre-swizzled: LDS[r][s] = global[r][s ^ (r&7)]
    int rsub = l >> 3;
    int kq_  = ((l & 7) ^ rsub) * 8;
    int rsw  = l15 & 7;              // read-side swizzle (row&7)

    const short* Ab = A  + (size_t)row0 * K;
    const short* Bb = BT + (size_t)col0 * K;

    const f32x4 zero4 = {0.f, 0.f, 0.f, 0.f};
    f32x4 acc[4][2];
    #pragma unroll
    for (int m = 0; m < 4; ++m)
        #pragma unroll
        for (int n = 0; n < 2; ++n) acc[m][n] = zero4;

    auto stage = [&](int bf, int k0) {
        #pragma unroll
        for (int i = 0; i < 4; ++i) {
            int r = i * 32 + w * 8 + rsub;
            gload16(Ab + (size_t)r * K + k0 + kq_, &As[bf][(i * 4 + w) * 512]);
        }
        {
            int r = w * 8 + rsub;
            gload16(Bb + (size_t)r * K + k0 + kq_, &Bs[bf][w * 512]);
            gload16(Bb + (size_t)(32 + r) * K + k0 + kq_, &Bs[bf][(4 + w) * 512]);
        }
    };

    stage(0, 0);
    waitvm0_barrier();

    int cur = 0;
    int NT = K >> 6;
    for (int t = 0; t < NT; ++t) {
        if (t + 1 < NT) stage(cur ^ 1, (t + 1) * 64);

        #pragma unroll
        for (int ks = 0; ks < 2; ++ks) {
            int slot = ((ks * 4 + lg) ^ rsw) * 8;
            short8v a[4], b[2];
            #pragma unroll
            for (int m = 0; m < 4; ++m)
                a[m] = *(const short8v*)&As[cur][(wr * 64 + m * 16 + l15) * 64 + slot];
            #pragma unroll
            for (int n = 0; n < 2; ++n)
                b[n] = *(const short8v*)&Bs[cur][(wc * 32 + n * 16 + l15) * 64 + slot];
            __builtin_amdgcn_s_setprio(1);
            #pragma unroll
            for (int m = 0; m < 4; ++m)
                #pragma unroll
                for (int n = 0; n < 2; ++n)
                    acc[m][n] = __builtin_amdgcn_mfma_f32_16x16x32_bf16(a[m], b[n], acc[m][n], 0, 0, 0);
            __builtin_amdgcn_s_setprio(0);
        }
        waitvm0_barrier();
        cur ^= 1;
    }

    #pragma unroll
    for (int n = 0; n < 2; ++n) {
        int col = col0 + wc * 32 + n * 16 + l15;
        float bv = bias[col];
        #pragma unroll
        for (int m = 0; m < 4; ++m) {
            #pragma unroll
            for (int i = 0; i < 4; ++i) {
                int row = row0 + wr * 64 + m * 16 + lg * 4 + i;
                size_t off = (size_t)row * N + col;
                float v = acc[m][n][i] + bv;
                if (RESID) v += resid[off];
                if (GELU)  v = 0.5f * v * (1.0f + erff(v * 0.70710678118654752f));
                if (OUTBF) Cb[off] = f2bf(v);
                else       Cf[off] = v;
            }
        }
    }
}

// ---------------------------------------------------------------------------
// Flash attention: swapped+key-permuted QK^T, P never leaves registers.
// Block = 64 q-rows of one (b,h); 4 waves x 16 q. K/V staged via
// global_load_lds into linear LDS, double-buffered (2-phase), with
// per-buffer XOR hashes giving 2-way reads:
//   hash_K(r) = ((r>>3)&3)<<1 | (r&1)   (matches permuted QK row pattern)
//   hash_V(r) = r&7                     (matches consecutive PV row pattern)
// ---------------------------------------------------------------------------
__global__ __launch_bounds__(256) void fattn_bf16(const short* __restrict__ qkvb,
                                                  const short* __restrict__ vtg,
                                                  short* __restrict__ attnout) {
    __shared__ short Ks[2][64 * 64];
    __shared__ short Vt[2][64 * 64];

    int tid = threadIdx.x;
    int l = tid & 63, w = tid >> 6;          // 4 waves
    int l15 = l & 15, lg = l >> 4;
    int qt = blockIdx.x, bh = blockIdx.y;
    int b = bh >> 3, h = bh & 7;
    int n0 = qt * 64;
    int qb = w * 16;
    const float kScale = 0.18033688011112042f;  // (1/8) * log2(e)
    const float kThr   = 44.361420f;            // 8 / kScale

    // read-side hashes (derived: kf-independent / df-independent)
    int hK = ((l15 >> 2) << 1) | (l15 & 1);
    int hV = l15 & 7;

    // Q b-fragments in registers (whole kernel)
    short8v bQ[2];
    #pragma unroll
    for (int ks = 0; ks < 2; ++ks)
        bQ[ks] = *(const short8v*)
            &qkvb[(size_t)(b * N_ + n0 + qb + l15) * 1536 + h * 64 + ks * 32 + lg * 8];

    const f32x4 zero4 = {0.f, 0.f, 0.f, 0.f};
    f32x4 o[4];
    float m_run = -3.402823466e+38f, l_run = 0.f;
    #pragma unroll
    for (int df = 0; df < 4; ++df) o[df] = zero4;

    // staging: wave w, i in {0,1} -> 8 rows (w*2+i)*8 + (l>>3), slot l&7
    int lr = l >> 3, lc = l & 7;

    auto stage = [&](int bf, int kn) {
        #pragma unroll
        for (int i = 0; i < 2; ++i) {
            int g = w * 2 + i;               // row group = r>>3
            int r = g * 8 + lr;
            int hKs = ((g & 3) << 1) | (lr & 1);
            gload16(&qkvb[(size_t)(b * N_ + kn + r) * 1536 + 512 + h * 64 + ((lc ^ hKs) << 3)],
                    &Ks[bf][g * 512]);
            gload16(&vtg[((size_t)bh * 64 + r) * N_ + kn + ((lc ^ lr) << 3)],
                    &Vt[bf][g * 512]);
        }
    };

    stage(0, 0);
    waitvm0_barrier();

    int cur = 0;
    for (int kt = 0; kt < 32; ++kt) {
        if (kt < 31) stage(cur ^ 1, (kt + 1) * 64);

        // ---- QK^T (swapped, key-permuted):
        // s[kf][i] = S'[key = (kf>>1)*32 + lg*8 + (kf&1)*4 + i][q = l15]
        f32x4 s[4];
        #pragma unroll
        for (int kf = 0; kf < 4; ++kf) {
            int krow = ((kf >> 1) << 5) + ((kf & 1) << 2) + ((l15 >> 2) << 3) + (l15 & 3);
            short8v aK0 = *(const short8v*)&Ks[cur][krow * 64 + ((lg ^ hK) << 3)];
            short8v aK1 = *(const short8v*)&Ks[cur][krow * 64 + (((4 + lg) ^ hK) << 3)];
            __builtin_amdgcn_s_setprio(1);
            s[kf] = __builtin_amdgcn_mfma_f32_16x16x32_bf16(aK0, bQ[0], zero4, 0, 0, 0);
            s[kf] = __builtin_amdgcn_mfma_f32_16x16x32_bf16(aK1, bQ[1], s[kf], 0, 0, 0);
            __builtin_amdgcn_s_setprio(0);
        }

        // ---- online softmax (defer-max THR=8) -> pack直接 into PV B-frags
        short8v bP[2];
        {
            float t0 = fmaxf(fmaxf(s[0][0], s[0][1]), fmaxf(s[0][2], s[0][3]));
            float t1 = fmaxf(fmaxf(s[1][0], s[1][1]), fmaxf(s[1][2], s[1][3]));
            float t2 = fmaxf(fmaxf(s[2][0], s[2][1]), fmaxf(s[2][2], s[2][3]));
            float t3 = fmaxf(fmaxf(s[3][0], s[3][1]), fmaxf(s[3][2], s[3][3]));
            float tm = fmaxf(fmaxf(t0, t1), fmaxf(t2, t3));
            tm = fmaxf(tm, __shfl_xor(tm, 16, 64));
            tm = fmaxf(tm, __shfl_xor(tm, 32, 64));
            bool defer = __all(tm <= m_run + kThr);
            float scl = 1.0f;
            if (!defer) {
                float mnew = fmaxf(m_run, tm);
                scl = exp2f((m_run - mnew) * kScale);
                m_run = mnew;
            }
            float nmk = -m_run * kScale;
            float ps = 0.f;
            #pragma unroll
            for (int kf = 0; kf < 4; ++kf) {
                #pragma unroll
                for (int i = 0; i < 4; ++i) {
                    float p = exp2f(fmaf(s[kf][i], kScale, nmk));
                    s[kf][i] = p;
                    ps += p;
                }
            }
            ps += __shfl_xor(ps, 16, 64);
            ps += __shfl_xor(ps, 32, 64);
            if (defer) {
                l_run += ps;
            } else {
                l_run = l_run * scl + ps;
                #pragma unroll
                for (int df = 0; df < 4; ++df) o[df] *= scl;
            }
            #pragma unroll
            for (int ks = 0; ks < 2; ++ks) {
                uint4v u;
                u[0] = cvtpk_bf16(s[2 * ks][0],     s[2 * ks][1]);
                u[1] = cvtpk_bf16(s[2 * ks][2],     s[2 * ks][3]);
                u[2] = cvtpk_bf16(s[2 * ks + 1][0], s[2 * ks + 1][1]);
                u[3] = cvtpk_bf16(s[2 * ks + 1][2], s[2 * ks + 1][3]);
                bP[ks] = __builtin_bit_cast(short8v, u);
            }
        }

        // ---- PV (swapped): O'[d][q] += V^T[d][k] * P[k][q]
        #pragma unroll
        for (int df = 0; df < 4; ++df) {
            int vrow = df * 16 + l15;
            short8v aV0 = *(const short8v*)&Vt[cur][vrow * 64 + ((lg ^ hV) << 3)];
            short8v aV1 = *(const short8v*)&Vt[cur][vrow * 64 + (((4 + lg) ^ hV) << 3)];
            __builtin_amdgcn_s_setprio(1);
            o[df] = __builtin_amdgcn_mfma_f32_16x16x32_bf16(aV0, bP[0], o[df], 0, 0, 0);
            o[df] = __builtin_amdgcn_mfma_f32_16x16x32_bf16(aV1, bP[1], o[df], 0, 0, 0);
            __builtin_amdgcn_s_setprio(0);
        }

        waitvm0_barrier();
        cur ^= 1;
    }

    // epilogue: normalize and store
    {
        float linv = 1.0f / l_run;
        size_t rowb = (size_t)(b * N_ + n0 + qb + l15) * D_ + h * 64;
        #pragma unroll
        for (int df = 0; df < 4; ++df) {
            uint2 uu;
            uu.x = cvtpk_bf16(o[df][0] * linv, o[df][1] * linv);
            uu.y = cvtpk_bf16(o[df][2] * linv, o[df][3] * linv);
            *(uint2*)&attnout[rowb + df * 16 + lg * 4] = uu;
        }
    }
}

// ---------------------------------------------------------------------------
extern "C" void kernel_launch(void* const* d_in, const int* in_sizes, int n_in,
                              void* d_out, int out_size, void* d_ws, size_t ws_size,
                              hipStream_t stream) {
    const float* x      = (const float*)d_in[0];
    const float* ln1_g  = (const float*)d_in[1];
    const float* ln1_b  = (const float*)d_in[2];
    const float* Wqkv   = (const float*)d_in[3];
    const float* bqkv   = (const float*)d_in[4];
    const float* Wproj  = (const float*)d_in[5];
    const float* bproj  = (const float*)d_in[6];
    const float* ln2_g  = (const float*)d_in[7];
    const float* ln2_b  = (const float*)d_in[8];
    const float* W1     = (const float*)d_in[9];
    const float* b1     = (const float*)d_in[10];
    const float* W2     = (const float*)d_in[11];
    const float* b2     = (const float*)d_in[12];
    float* out = (float*)d_out;

    char* ws = (char*)d_ws;
    short* h_bf    = (short*)(ws + (size_t)0);
    short* qkv_bf  = (short*)(ws + ((size_t)8  << 20));
    short* vtg     = (short*)(ws + ((size_t)32 << 20));
    short* attn_bf = (short*)(ws + ((size_t)40 << 20));
    float* x2      = (float*)(ws + ((size_t)48 << 20));
    short* h2_bf   = (short*)(ws + ((size_t)64 << 20));
    short* ffh_bf  = (short*)(ws + ((size_t)72 << 20));
    short* WTqkv   = (short*)(ws + ((size_t)104 << 20));
    short* WTproj  = (short*)(ws + ((size_t)106 << 20));
    short* WT1     = (short*)(ws + ((size_t)108 << 20));
    short* WT2     = (short*)(ws + ((size_t)110 << 20));

    dim3 blk(256);

    // weight transposes (bf16)
    wt_kernel<<<dim3(24, 8),  blk, 0, stream>>>(Wqkv,  WTqkv,  512,  1536);
    wt_kernel<<<dim3(8, 8),   blk, 0, stream>>>(Wproj, WTproj, 512,  512);
    wt_kernel<<<dim3(32, 8),  blk, 0, stream>>>(W1,    WT1,    512,  2048);
    wt_kernel<<<dim3(8, 32),  blk, 0, stream>>>(W2,    WT2,    2048, 512);

    // 1. h = LN1(x)  (bf16)
    ln_bf16_kernel<<<ROWS_ / 4, blk, 0, stream>>>(x, ln1_g, ln1_b, h_bf);

    // 2. qkv = h @ Wqkv + bqkv  (bf16 out)
    gemm_bf16<false, false, true><<<dim3(24, 64), blk, 0, stream>>>(
        h_bf, WTqkv, bqkv, nullptr, nullptr, qkv_bf, ROWS_, 1536, 512);

    // 3a. V transpose per head
    vt_kernel<<<dim3(32, 32), blk, 0, stream>>>(qkv_bf, vtg);

    // 3b. attention (bf16 out): 64 q-rows/block, 1024 blocks
    fattn_bf16<<<dim3(32, 32), blk, 0, stream>>>(qkv_bf, vtg, attn_bf);

    // 4. x2 = x + attn @ Wproj + bproj  (fp32 out)
    gemm_bf16<false, true, false><<<dim3(8, 64), blk, 0, stream>>>(
        attn_bf, WTproj, bproj, x, x2, nullptr, ROWS_, 512, 512);

    // 5. h2 = LN2(x2)  (bf16)
    ln_bf16_kernel<<<ROWS_ / 4, blk, 0, stream>>>(x2, ln2_g, ln2_b, h2_bf);

    // 6. ffh = gelu(h2 @ W1 + b1)  (bf16 out)
    gemm_bf16<true, false, true><<<dim3(32, 64), blk, 0, stream>>>(
        h2_bf, WT1, b1, nullptr, nullptr, ffh_bf, ROWS_, 2048, 512);

    // 7. out = x2 + ffh @ W2 + b2  (fp32 out)
    gemm_bf16<false, true, false><<<dim3(8, 64), blk, 0, stream>>>(
        ffh_bf, WT2, b2, x2, out, nullptr, ROWS_, 512, 2048);
}

// Round 8
// 216.040 us; speedup vs baseline: 1.1345x; 1.0577x over previous
//
#include <hip/hip_runtime.h>

#define B_ 4
#define N_ 2048
#define D_ 512
#define H_ 8
#define DH_ 64
#define ROWS_ 8192

typedef float f32x4 __attribute__((ext_vector_type(4)));
typedef short short8v __attribute__((ext_vector_type(8)));
typedef short short4v __attribute__((ext_vector_type(4)));
typedef unsigned uint4v __attribute__((ext_vector_type(4)));

__device__ __forceinline__ short f2bf(float f) {
    unsigned u = __builtin_bit_cast(unsigned, f);
    u += 0x7FFFu + ((u >> 16) & 1u);   // round-to-nearest-even
    return (short)(u >> 16);
}

__device__ __forceinline__ unsigned cvtpk_bf16(float lo, float hi) {
    unsigned r;
    asm("v_cvt_pk_bf16_f32 %0, %1, %2" : "=v"(r) : "v"(lo), "v"(hi));
    return r;
}

// async global->LDS, 16B per lane; lds dest = wave-uniform base + lane*16.
__device__ __forceinline__ void gload16(const void* g, void* l) {
    __builtin_amdgcn_global_load_lds(
        (const __attribute__((address_space(1))) unsigned int*)g,
        (__attribute__((address_space(3))) unsigned int*)l, 16, 0, 0);
}

__device__ __forceinline__ void waitvm0_barrier() {
    asm volatile("s_waitcnt vmcnt(0)" ::: "memory");
    __builtin_amdgcn_s_barrier();
}

// ---------------------------------------------------------------------------
// LayerNorm fp32-in -> bf16-out. One wave per row of 512; 4 rows/block.
// ---------------------------------------------------------------------------
__global__ __launch_bounds__(256) void ln_bf16_kernel(const float* __restrict__ x,
                                                      const float* __restrict__ g,
                                                      const float* __restrict__ bb,
                                                      short* __restrict__ out) {
    int wave = threadIdx.x >> 6;
    int lane = threadIdx.x & 63;
    int row  = blockIdx.x * 4 + wave;
    const float* xr = x + (size_t)row * D_;

    float4 v0 = ((const float4*)xr)[lane * 2 + 0];
    float4 v1 = ((const float4*)xr)[lane * 2 + 1];

    float s = v0.x + v0.y + v0.z + v0.w + v1.x + v1.y + v1.z + v1.w;
    #pragma unroll
    for (int off = 32; off; off >>= 1) s += __shfl_xor(s, off, 64);
    float mu = s * (1.0f / D_);

    float d0 = v0.x - mu, d1 = v0.y - mu, d2 = v0.z - mu, d3 = v0.w - mu;
    float d4 = v1.x - mu, d5 = v1.y - mu, d6 = v1.z - mu, d7 = v1.w - mu;
    float vs = d0*d0 + d1*d1 + d2*d2 + d3*d3 + d4*d4 + d5*d5 + d6*d6 + d7*d7;
    #pragma unroll
    for (int off = 32; off; off >>= 1) vs += __shfl_xor(vs, off, 64);
    float rstd = rsqrtf(vs * (1.0f / D_) + 1e-5f);

    float4 g0 = ((const float4*)g)[lane * 2 + 0];
    float4 g1 = ((const float4*)g)[lane * 2 + 1];
    float4 b0 = ((const float4*)bb)[lane * 2 + 0];
    float4 b1 = ((const float4*)bb)[lane * 2 + 1];

    short8v ov;
    ov[0] = f2bf(d0 * rstd * g0.x + b0.x);
    ov[1] = f2bf(d1 * rstd * g0.y + b0.y);
    ov[2] = f2bf(d2 * rstd * g0.z + b0.z);
    ov[3] = f2bf(d3 * rstd * g0.w + b0.w);
    ov[4] = f2bf(d4 * rstd * g1.x + b1.x);
    ov[5] = f2bf(d5 * rstd * g1.y + b1.y);
    ov[6] = f2bf(d6 * rstd * g1.z + b1.z);
    ov[7] = f2bf(d7 * rstd * g1.w + b1.w);
    *(short8v*)&out[(size_t)row * D_ + lane * 8] = ov;
}

// ---------------------------------------------------------------------------
// Weight transpose + cvt: W[K][N] fp32 -> WT[N][K] bf16. 64x64 tile per block.
// ---------------------------------------------------------------------------
__global__ __launch_bounds__(256) void wt_kernel(const float* __restrict__ W,
                                                 short* __restrict__ WT,
                                                 int K, int N) {
    __shared__ short Ts[64][72];
    int tid = threadIdx.x;
    int n0 = blockIdx.x * 64, k0 = blockIdx.y * 64;

    #pragma unroll
    for (int i = 0; i < 4; ++i) {
        int idx = tid + i * 256;            // 1024 float4 chunks
        int k = idx >> 4, nq = (idx & 15) * 4;
        float4 wv = *(const float4*)&W[(size_t)(k0 + k) * N + n0 + nq];
        short4v t;
        t[0] = f2bf(wv.x); t[1] = f2bf(wv.y); t[2] = f2bf(wv.z); t[3] = f2bf(wv.w);
        *(short4v*)&Ts[k][nq] = t;
    }
    __syncthreads();

    int n = tid >> 2, kq = (tid & 3) * 16;
    short8v o0, o1;
    #pragma unroll
    for (int j = 0; j < 8; ++j) { o0[j] = Ts[kq + j][n]; o1[j] = Ts[kq + 8 + j][n]; }
    *(short8v*)&WT[(size_t)(n0 + n) * K + k0 + kq]     = o0;
    *(short8v*)&WT[(size_t)(n0 + n) * K + k0 + kq + 8] = o1;
}

// ---------------------------------------------------------------------------
// V transpose per head: qkv_bf[row][1536] (v at +1024) -> vtg[bh][64 d][2048 n]
// ---------------------------------------------------------------------------
__global__ __launch_bounds__(256) void vt_kernel(const short* __restrict__ qkvb,
                                                 short* __restrict__ vtg) {
    __shared__ short Ts[64][72];
    int tid = threadIdx.x;
    int n0 = blockIdx.x * 64;
    int bh = blockIdx.y;
    int b = bh >> 3, h = bh & 7;

    #pragma unroll
    for (int i = 0; i < 2; ++i) {
        int idx = tid + i * 256;            // 512 chunks of 8 bf16
        int n = idx >> 3, dq = (idx & 7) * 8;
        *(short8v*)&Ts[n][dq] =
            *(const short8v*)&qkvb[(size_t)(b * N_ + n0 + n) * 1536 + 1024 + h * 64 + dq];
    }
    __syncthreads();

    int d = tid >> 2, nq = (tid & 3) * 16;
    short8v o0, o1;
    #pragma unroll
    for (int j = 0; j < 8; ++j) { o0[j] = Ts[nq + j][d]; o1[j] = Ts[nq + 8 + j][d]; }
    size_t base = ((size_t)bh * 64 + d) * N_ + n0 + nq;
    *(short8v*)&vtg[base]     = o0;
    *(short8v*)&vtg[base + 8] = o1;
}

// ---------------------------------------------------------------------------
// bf16 MFMA GEMM: 128x64 tile, BK=64, double-buffered global_load_lds.
// Loop unrolled by 2 with literal buffer indices so every LDS read is
// VGPR-base + compile-time immediate; staging via pointer += stride.
// Linear LDS + both-sides XOR swizzle. 4 waves 2x2.
// ---------------------------------------------------------------------------
template<bool GELU, bool RESID, bool OUTBF>
__global__ __launch_bounds__(256) void gemm_bf16(const short* __restrict__ A,
                                                 const short* __restrict__ BT,
                                                 const float* __restrict__ bias,
                                                 const float* __restrict__ resid,
                                                 float* __restrict__ Cf,
                                                 short* __restrict__ Cb,
                                                 int M, int N, int K) {
    __shared__ short As[2][8192];   // [bf][128*64]
    __shared__ short Bs[2][4096];   // [bf][64*64]
    int tid = threadIdx.x;
    int l = tid & 63, w = tid >> 6;
    int wr = w >> 1, wc = w & 1;
    int l15 = l & 15, lg = l >> 4;
    int row0 = blockIdx.y * 128, col0 = blockIdx.x * 64;

    // staging: lane covers LDS row (group*8 + (l>>3)), slot (l&7);
    // source col pre-swizzled: LDS[r][s] = global[r][s ^ (r&7)]
    int rsub = l >> 3;
    int kq_  = ((l & 7) ^ rsub) * 8;
    int rsw  = l15 & 7;              // read-side swizzle (row&7)

    const short* ap[4];
    const short* bp[2];
    #pragma unroll
    for (int i = 0; i < 4; ++i)
        ap[i] = A + (size_t)(row0 + i * 32 + w * 8 + rsub) * K + kq_;
    bp[0] = BT + (size_t)(col0 + w * 8 + rsub) * K + kq_;
    bp[1] = BT + (size_t)(col0 + 32 + w * 8 + rsub) * K + kq_;

    // per-lane LDS read offsets (shorts); ks=1 slot = ks=0 slot XOR 4
    int aoff0 = (wr * 64 + l15) * 64 + ((lg ^ rsw)) * 8;
    int aoff1 = (wr * 64 + l15) * 64 + (((4 + lg) ^ rsw)) * 8;
    int boff0 = (wc * 32 + l15) * 64 + ((lg ^ rsw)) * 8;
    int boff1 = (wc * 32 + l15) * 64 + (((4 + lg) ^ rsw)) * 8;

    const f32x4 zero4 = {0.f, 0.f, 0.f, 0.f};
    f32x4 acc[4][2];
    #pragma unroll
    for (int m = 0; m < 4; ++m)
        #pragma unroll
        for (int n = 0; n < 2; ++n) acc[m][n] = zero4;

    auto stage = [&](int bf) {
        #pragma unroll
        for (int i = 0; i < 4; ++i) {
            gload16(ap[i], &As[bf][(i * 4 + w) * 512]);
            ap[i] += 64;
        }
        gload16(bp[0], &Bs[bf][w * 512]);       bp[0] += 64;
        gload16(bp[1], &Bs[bf][(4 + w) * 512]); bp[1] += 64;
    };

    auto compute = [&](int bf) {
        #pragma unroll
        for (int ks = 0; ks < 2; ++ks) {
            short8v a[4], bfr[2];
            #pragma unroll
            for (int m = 0; m < 4; ++m)
                a[m] = *(const short8v*)&As[bf][(ks ? aoff1 : aoff0) + m * 1024];
            #pragma unroll
            for (int n = 0; n < 2; ++n)
                bfr[n] = *(const short8v*)&Bs[bf][(ks ? boff1 : boff0) + n * 1024];
            __builtin_amdgcn_s_setprio(1);
            #pragma unroll
            for (int m = 0; m < 4; ++m)
                #pragma unroll
                for (int n = 0; n < 2; ++n)
                    acc[m][n] = __builtin_amdgcn_mfma_f32_16x16x32_bf16(a[m], bfr[n], acc[m][n], 0, 0, 0);
            __builtin_amdgcn_s_setprio(0);
        }
    };

    stage(0);
    waitvm0_barrier();

    int NH = K >> 7;                 // NT/2
    for (int t2 = 0; t2 < NH; ++t2) {
        stage(1);
        compute(0);
        waitvm0_barrier();
        if (t2 + 1 < NH) stage(0);
        compute(1);
        waitvm0_barrier();
    }

    #pragma unroll
    for (int n = 0; n < 2; ++n) {
        int col = col0 + wc * 32 + n * 16 + l15;
        float bv = bias[col];
        #pragma unroll
        for (int m = 0; m < 4; ++m) {
            #pragma unroll
            for (int i = 0; i < 4; ++i) {
                int row = row0 + wr * 64 + m * 16 + lg * 4 + i;
                size_t off = (size_t)row * N + col;
                float v = acc[m][n][i] + bv;
                if (RESID) v += resid[off];
                if (GELU)  v = 0.5f * v * (1.0f + erff(v * 0.70710678118654752f));
                if (OUTBF) Cb[off] = f2bf(v);
                else       Cf[off] = v;
            }
        }
    }
}

// ---------------------------------------------------------------------------
// Flash attention: swapped+key-permuted QK^T, P never leaves registers.
// Block = 64 q-rows of one (b,h); 4 waves x 16 q. K/V via global_load_lds,
// double-buffered, unrolled-by-2 (literal buffer indices -> immediate LDS
// addressing). Row-sum computed by MFMA with a ones A-operand (no shuffles);
// defer-max THR=8.
// ---------------------------------------------------------------------------
__global__ __launch_bounds__(256) void fattn_bf16(const short* __restrict__ qkvb,
                                                  const short* __restrict__ vtg,
                                                  short* __restrict__ attnout) {
    __shared__ short Ks[2][4096];
    __shared__ short Vt[2][4096];

    int tid = threadIdx.x;
    int l = tid & 63, w = tid >> 6;          // 4 waves
    int l15 = l & 15, lg = l >> 4;
    int qt = blockIdx.x, bh = blockIdx.y;
    int b = bh >> 3, h = bh & 7;
    int n0 = qt * 64;
    int qb = w * 16;
    const float kScale = 0.18033688011112042f;  // (1/8) * log2(e)
    const float kThr   = 44.361420f;            // 8 / kScale

    // read-side hashes + permuted row base
    int hK = ((l15 >> 2) << 1) | (l15 & 1);
    int hV = l15 & 7;
    int kperm = ((l15 >> 2) << 3) + (l15 & 3);

    // LDS read offsets (shorts); kf/df parts become compile-time immediates
    int koff0 = kperm * 64 + (lg ^ hK) * 8;
    int koff1 = kperm * 64 + (((4 + lg) ^ hK)) * 8;
    int voff0 = l15 * 64 + (lg ^ hV) * 8;
    int voff1 = l15 * 64 + (((4 + lg) ^ hV)) * 8;

    // Q b-fragments in registers (whole kernel)
    short8v bQ[2];
    #pragma unroll
    for (int ks = 0; ks < 2; ++ks)
        bQ[ks] = *(const short8v*)
            &qkvb[(size_t)(b * N_ + n0 + qb + l15) * 1536 + h * 64 + ks * 32 + lg * 8];

    short8v ones;
    #pragma unroll
    for (int j = 0; j < 8; ++j) ones[j] = (short)0x3F80;   // bf16 1.0

    const f32x4 zero4 = {0.f, 0.f, 0.f, 0.f};
    f32x4 o[4], l_acc = zero4;
    float m_run = -3.402823466e+38f;
    #pragma unroll
    for (int df = 0; df < 4; ++df) o[df] = zero4;

    // staging: wave w, i in {0,1} -> 8 rows (w*2+i)*8 + (l>>3), slot l&7
    int lr = l >> 3, lc = l & 7;
    const short* kp[2];
    const short* vp[2];
    #pragma unroll
    for (int i = 0; i < 2; ++i) {
        int g = w * 2 + i, r = g * 8 + lr;
        int hKs = ((g & 3) << 1) | (lr & 1);
        kp[i] = &qkvb[(size_t)(b * N_ + r) * 1536 + 512 + h * 64 + ((lc ^ hKs) << 3)];
        vp[i] = &vtg[((size_t)bh * 64 + r) * N_ + ((lc ^ lr) << 3)];
    }

    auto stage = [&](int bf) {
        #pragma unroll
        for (int i = 0; i < 2; ++i) {
            int g = w * 2 + i;
            gload16(kp[i], &Ks[bf][g * 512]); kp[i] += 64 * 1536;
            gload16(vp[i], &Vt[bf][g * 512]); vp[i] += 64;
        }
    };

    auto compute = [&](int bf) {
        // ---- QK^T (swapped, key-permuted):
        // s[kf][i] = S'[key = (kf>>1)*32 + lg*8 + (kf&1)*4 + i][q = l15]
        f32x4 s[4];
        #pragma unroll
        for (int kf = 0; kf < 4; ++kf) {
            short8v aK0 = *(const short8v*)&Ks[bf][koff0 + (kf >> 1) * 2048 + (kf & 1) * 256];
            short8v aK1 = *(const short8v*)&Ks[bf][koff1 + (kf >> 1) * 2048 + (kf & 1) * 256];
            __builtin_amdgcn_s_setprio(1);
            s[kf] = __builtin_amdgcn_mfma_f32_16x16x32_bf16(aK0, bQ[0], zero4, 0, 0, 0);
            s[kf] = __builtin_amdgcn_mfma_f32_16x16x32_bf16(aK1, bQ[1], s[kf], 0, 0, 0);
            __builtin_amdgcn_s_setprio(0);
        }

        // ---- online softmax (defer-max); sum comes from the ones-MFMA below
        short8v bP[2];
        {
            float t0 = fmaxf(fmaxf(s[0][0], s[0][1]), fmaxf(s[0][2], s[0][3]));
            float t1 = fmaxf(fmaxf(s[1][0], s[1][1]), fmaxf(s[1][2], s[1][3]));
            float t2 = fmaxf(fmaxf(s[2][0], s[2][1]), fmaxf(s[2][2], s[2][3]));
            float t3 = fmaxf(fmaxf(s[3][0], s[3][1]), fmaxf(s[3][2], s[3][3]));
            float tm = fmaxf(fmaxf(t0, t1), fmaxf(t2, t3));
            tm = fmaxf(tm, __shfl_xor(tm, 16, 64));
            tm = fmaxf(tm, __shfl_xor(tm, 32, 64));
            bool defer = __all(tm <= m_run + kThr);
            if (!defer) {
                float mnew = fmaxf(m_run, tm);
                float scl = exp2f((m_run - mnew) * kScale);
                m_run = mnew;
                #pragma unroll
                for (int df = 0; df < 4; ++df) o[df] *= scl;
                l_acc[0] *= scl;
            }
            float nmk = -m_run * kScale;
            #pragma unroll
            for (int kf = 0; kf < 4; ++kf)
                #pragma unroll
                for (int i = 0; i < 4; ++i)
                    s[kf][i] = exp2f(fmaf(s[kf][i], kScale, nmk));
            #pragma unroll
            for (int ks = 0; ks < 2; ++ks) {
                uint4v u;
                u[0] = cvtpk_bf16(s[2 * ks][0],     s[2 * ks][1]);
                u[1] = cvtpk_bf16(s[2 * ks][2],     s[2 * ks][3]);
                u[2] = cvtpk_bf16(s[2 * ks + 1][0], s[2 * ks + 1][1]);
                u[3] = cvtpk_bf16(s[2 * ks + 1][2], s[2 * ks + 1][3]);
                bP[ks] = __builtin_bit_cast(short8v, u);
            }
        }

        // ---- row-sum via ones-MFMA: l_acc[*][q] += sum_k P[k][q]
        // ---- PV (swapped): O'[d][q] += V^T[d][k] * P[k][q]
        __builtin_amdgcn_s_setprio(1);
        l_acc = __builtin_amdgcn_mfma_f32_16x16x32_bf16(ones, bP[0], l_acc, 0, 0, 0);
        l_acc = __builtin_amdgcn_mfma_f32_16x16x32_bf16(ones, bP[1], l_acc, 0, 0, 0);
        __builtin_amdgcn_s_setprio(0);
        #pragma unroll
        for (int df = 0; df < 4; ++df) {
            short8v aV0 = *(const short8v*)&Vt[bf][voff0 + df * 1024];
            short8v aV1 = *(const short8v*)&Vt[bf][voff1 + df * 1024];
            __builtin_amdgcn_s_setprio(1);
            o[df] = __builtin_amdgcn_mfma_f32_16x16x32_bf16(aV0, bP[0], o[df], 0, 0, 0);
            o[df] = __builtin_amdgcn_mfma_f32_16x16x32_bf16(aV1, bP[1], o[df], 0, 0, 0);
            __builtin_amdgcn_s_setprio(0);
        }
    };

    stage(0);
    waitvm0_barrier();

    for (int t2 = 0; t2 < 16; ++t2) {
        stage(1);
        compute(0);
        waitvm0_barrier();
        if (t2 + 1 < 16) stage(0);
        compute(1);
        waitvm0_barrier();
    }

    // epilogue: normalize and store
    {
        float linv = 1.0f / l_acc[0];
        size_t rowb = (size_t)(b * N_ + n0 + qb + l15) * D_ + h * 64;
        #pragma unroll
        for (int df = 0; df < 4; ++df) {
            uint2 uu;
            uu.x = cvtpk_bf16(o[df][0] * linv, o[df][1] * linv);
            uu.y = cvtpk_bf16(o[df][2] * linv, o[df][3] * linv);
            *(uint2*)&attnout[rowb + df * 16 + lg * 4] = uu;
        }
    }
}

// ---------------------------------------------------------------------------
extern "C" void kernel_launch(void* const* d_in, const int* in_sizes, int n_in,
                              void* d_out, int out_size, void* d_ws, size_t ws_size,
                              hipStream_t stream) {
    const float* x      = (const float*)d_in[0];
    const float* ln1_g  = (const float*)d_in[1];
    const float* ln1_b  = (const float*)d_in[2];
    const float* Wqkv   = (const float*)d_in[3];
    const float* bqkv   = (const float*)d_in[4];
    const float* Wproj  = (const float*)d_in[5];
    const float* bproj  = (const float*)d_in[6];
    const float* ln2_g  = (const float*)d_in[7];
    const float* ln2_b  = (const float*)d_in[8];
    const float* W1     = (const float*)d_in[9];
    const float* b1     = (const float*)d_in[10];
    const float* W2     = (const float*)d_in[11];
    const float* b2     = (const float*)d_in[12];
    float* out = (float*)d_out;

    char* ws = (char*)d_ws;
    short* h_bf    = (short*)(ws + (size_t)0);
    short* qkv_bf  = (short*)(ws + ((size_t)8  << 20));
    short* vtg     = (short*)(ws + ((size_t)32 << 20));
    short* attn_bf = (short*)(ws + ((size_t)40 << 20));
    float* x2      = (float*)(ws + ((size_t)48 << 20));
    short* h2_bf   = (short*)(ws + ((size_t)64 << 20));
    short* ffh_bf  = (short*)(ws + ((size_t)72 << 20));
    short* WTqkv   = (short*)(ws + ((size_t)104 << 20));
    short* WTproj  = (short*)(ws + ((size_t)106 << 20));
    short* WT1     = (short*)(ws + ((size_t)108 << 20));
    short* WT2     = (short*)(ws + ((size_t)110 << 20));

    dim3 blk(256);

    // weight transposes (bf16)
    wt_kernel<<<dim3(24, 8),  blk, 0, stream>>>(Wqkv,  WTqkv,  512,  1536);
    wt_kernel<<<dim3(8, 8),   blk, 0, stream>>>(Wproj, WTproj, 512,  512);
    wt_kernel<<<dim3(32, 8),  blk, 0, stream>>>(W1,    WT1,    512,  2048);
    wt_kernel<<<dim3(8, 32),  blk, 0, stream>>>(W2,    WT2,    2048, 512);

    // 1. h = LN1(x)  (bf16)
    ln_bf16_kernel<<<ROWS_ / 4, blk, 0, stream>>>(x, ln1_g, ln1_b, h_bf);

    // 2. qkv = h @ Wqkv + bqkv  (bf16 out)
    gemm_bf16<false, false, true><<<dim3(24, 64), blk, 0, stream>>>(
        h_bf, WTqkv, bqkv, nullptr, nullptr, qkv_bf, ROWS_, 1536, 512);

    // 3a. V transpose per head
    vt_kernel<<<dim3(32, 32), blk, 0, stream>>>(qkv_bf, vtg);

    // 3b. attention (bf16 out): 64 q-rows/block, 1024 blocks
    fattn_bf16<<<dim3(32, 32), blk, 0, stream>>>(qkv_bf, vtg, attn_bf);

    // 4. x2 = x + attn @ Wproj + bproj  (fp32 out)
    gemm_bf16<false, true, false><<<dim3(8, 64), blk, 0, stream>>>(
        attn_bf, WTproj, bproj, x, x2, nullptr, ROWS_, 512, 512);

    // 5. h2 = LN2(x2)  (bf16)
    ln_bf16_kernel<<<ROWS_ / 4, blk, 0, stream>>>(x2, ln2_g, ln2_b, h2_bf);

    // 6. ffh = gelu(h2 @ W1 + b1)  (bf16 out)
    gemm_bf16<true, false, true><<<dim3(32, 64), blk, 0, stream>>>(
        h2_bf, WT1, b1, nullptr, nullptr, ffh_bf, ROWS_, 2048, 512);

    // 7. out = x2 + ffh @ W2 + b2  (fp32 out)
    gemm_bf16<false, true, false><<<dim3(8, 64), blk, 0, stream>>>(
        ffh_bf, WT2, b2, x2, out, nullptr, ROWS_, 512, 2048);
}